// Round 3
// baseline (122.519 us; speedup 1.0000x reference)
//
#include <hip/hip_runtime.h>
#include <math.h>

#define EPSV 1e-8f

// ---------------- math ------------------------------------------------------
// Per node n with unit incident dirs d_i = (cos phi_i, sin phi_i):
//   0.5*(S2-S4) = (u^2 - C^2 - S^2)/16,  C = sum cos(4 phi_i), S = sum sin(4 phi_i)
//   u = deg - z (z = zero-length self-edge dirs, which contribute nothing)
// Record (u32): [31] z | [30:23] local node id (8b) | [22:11] c4q | [10:0] s4q
// Accumulator (u64): {z:4 @60 | deg:8 @52 | c4sum:26 @26 | s4sum:26 @0}
//
// ROUND-1 LESSON: global atomics on gfx950 execute memory-side (past XCD L2):
//   4M u64 atomics -> ~128 MB HBM WRITE_SIZE, 181 us. Scatter-by-atomics dead.
// ROUND-2 LESSON: bucket_kernel's global READ pattern is off the critical path
//   (16x line-efficiency improvement moved total by 0.2 us). Remaining costs:
//   bin_kernel's second pass (pos re-gathers + make_record recompute) and the
//   final-kernel launch. This round: stage rec in LDS (compute once), merge
//   final into bucket via memory-side f64 atomics + last-block-done.
static constexpr double QC = 1.0 / 1024.0;
static constexpr double QS = 1.0 / 512.0;

static constexpr int BLOG = 8;               // 256 nodes per bucket
static constexpr int NPB = 1 << BLOG;
static constexpr int NBIN = 512;             // bin blocks (each sorts its own chunk)
static constexpr int SRTN = 8192;            // LDS sort capacity (records)
static constexpr int CHMAX = SRTN / 2;       // max edges per bin chunk
static constexpr int NODE_BLOCKS = 256;      // fallback path

__device__ __forceinline__ unsigned int make_record(float dx, float dy) {
    float n2 = dx * dx + dy * dy;
    if (n2 > EPSV * EPSV) {
        float inv = 1.0f / n2;
        // double angle twice without sqrt: c2=cos2phi, s2=sin2phi from (dx,dy)
        float c2 = (dx * dx - dy * dy) * inv;
        float s2 = (2.0f * dx * dy) * inv;
        float c4 = c2 * c2 - s2 * s2;
        float s4 = 2.0f * c2 * s2;
        c4 = fminf(fmaxf(c4, -1.0f), 1.0f);
        s4 = fminf(fmaxf(s4, -1.0f), 1.0f);
        unsigned int c4q = (unsigned int)__float2int_rn((c4 + 1.0f) * 1024.0f);
        unsigned int s4q = (unsigned int)__float2int_rn((s4 + 1.0f) * 512.0f);
        return (c4q << 11) | s4q;
    }
    return (1u << 31) | (1024u << 11) | 512u;   // zero-length dir (self-edge)
}

__device__ __forceinline__ unsigned long long rec_to_val(unsigned int r) {
    return (((unsigned long long)(r >> 31)) << 60) | (1ull << 52)
         | (((unsigned long long)((r >> 11) & 0xFFFu)) << 26)
         | (unsigned long long)(r & 0x7FFu);
}

__device__ __forceinline__ void decode_accum(unsigned long long a, double& pls, double& npr) {
    double s4sum = (double)(a & 0x3FFFFFFull);
    double c4sum = (double)((a >> 26) & 0x3FFFFFFull);
    double deg = (double)((a >> 52) & 0xFFull);
    double z = (double)(a >> 60);
    double u = deg - z;
    double C = c4sum * QC - deg;
    double S = s4sum * QS - deg;
    pls += (u * u - C * C - S * S) * 0.0625;
    npr += 0.5 * deg * (deg - 1.0);
}

// ---------------- phase 1: per-block counting sort of records ---------------
// Single-compute version: pass 1 gathers pos + computes rec ONCE, staged in
// LDS recbuf (16 KB). Pass 2 re-reads only s,d (coalesced, L2-hot) and places
// staged recs. LDS total 52 KB -> still 2 blocks/CU.
__global__ __launch_bounds__(256) void bin_kernel(
    const float2* __restrict__ pos,
    const int* __restrict__ ei,        // (2,E): src row then dst row
    int E, int NB, int chunk, int rstride,
    unsigned short* __restrict__ ofs_out,  // [NBIN][NB+1] exclusive offsets
    unsigned int* __restrict__ buf,        // [NBIN][rstride] sorted records
    unsigned long long* __restrict__ hdr)  // [gs0,gs1,counter,pad] zeroed here
{
    __shared__ unsigned int srt[SRTN];
    __shared__ unsigned int recbuf[CHMAX];
    __shared__ unsigned int hist[512];   // counts, then cursors
    __shared__ unsigned int scan[512];
    int blk = blockIdx.x;
    int t = threadIdx.x;
    if (blk == 0 && t < 4) hdr[t] = 0ull;   // zero accumulators + done-counter
    int e0 = blk * chunk;
    int e1 = min(E, e0 + chunk);
    int cl = max(0, e1 - e0);
    const int* src = ei;
    const int* dst = ei + E;

    hist[t] = 0; hist[t + 256] = 0;
    __syncthreads();
    // pass 1: histogram + compute record once, stage in LDS
    for (int e = e0 + t; e < e1; e += 256) {
        int s = src[e], d = dst[e];
        atomicAdd(&hist[s >> BLOG], 1u);
        atomicAdd(&hist[d >> BLOG], 1u);
        float2 ps = pos[s], pd = pos[d];
        recbuf[e - e0] = make_record(pd.x - ps.x, pd.y - ps.y);
    }
    __syncthreads();
    // inclusive Hillis-Steele scan over 512 slots
    scan[t] = hist[t]; scan[t + 256] = hist[t + 256];
    __syncthreads();
    for (int d = 1; d < 512; d <<= 1) {
        unsigned a0 = scan[t] + ((t >= d) ? scan[t - d] : 0u);
        int t2 = t + 256;
        unsigned a1 = scan[t2] + ((t2 >= d) ? scan[t2 - d] : 0u);
        __syncthreads();
        scan[t] = a0; scan[t2] = a1;
        __syncthreads();
    }
    // exclusive offsets; emit row; convert hist -> cursors
    unsigned ex0 = scan[t] - hist[t];
    unsigned ex1 = scan[t + 256] - hist[t + 256];
    size_t row = (size_t)blk * (size_t)(NB + 1);
    if (t < NB) ofs_out[row + t] = (unsigned short)ex0;
    if (t + 256 < NB) ofs_out[row + t + 256] = (unsigned short)ex1;
    if (t == 0) ofs_out[row + NB] = (unsigned short)(2 * cl);
    __syncthreads();
    hist[t] = ex0; hist[t + 256] = ex1;
    __syncthreads();
    // pass 2: place staged records into LDS sorted array (s,d re-read from L2)
    for (int e = e0 + t; e < e1; e += 256) {
        int s = src[e], d = dst[e];
        unsigned int rec = recbuf[e - e0];
        unsigned is = atomicAdd(&hist[s >> BLOG], 1u);
        srt[is] = rec | ((unsigned)(s & (NPB - 1)) << 23);
        unsigned it = atomicAdd(&hist[d >> BLOG], 1u);
        srt[it] = rec | ((unsigned)(d & (NPB - 1)) << 23);
    }
    __syncthreads();
    // coalesced copy-out of the block's private sorted region
    unsigned int* dstb = buf + (size_t)blk * (size_t)rstride;
    int nrec = 2 * cl;
    for (int i = t; i < nrec; i += 256) dstb[i] = srt[i];
}

// ---------------- phase 2: per-bucket LDS reduction + fused final -----------
// Ends with memory-side f64 atomicAdd into hdr (gs0=pls, gs1=npr); the LAST
// block (device atomic counter) reads totals via atomicAdd(p, 0.0) — also
// memory-side, so no cross-XCD L2 staleness — and writes out[0].
__global__ __launch_bounds__(512) void bucket_kernel(
    const unsigned int* __restrict__ buf,
    const unsigned short* __restrict__ ofs,
    int rstride, int NB, int nbin,
    unsigned long long* __restrict__ hdr,
    float* __restrict__ out)
{
    __shared__ unsigned long long acc[8][NPB];   // replicated per wave (8 waves)
    __shared__ unsigned int so0[NBIN], so1[NBIN];
    __shared__ double sha[8], shb[8];
    int b = blockIdx.x;
    int t = threadIdx.x;
    int wid = t >> 6;
    for (int i = t; i < 8 * NPB; i += 512)
        ((unsigned long long*)acc)[i] = 0ull;
    // stage this bucket's run offsets (one strided burst)
    if (t < nbin) {
        size_t row = (size_t)t * (size_t)(NB + 1);
        so0[t] = ofs[row + b];
        so1[t] = ofs[row + b + 1];
    }
    __syncthreads();

    int g = t >> 4;          // group id 0..31
    int l = t & 15;          // lane within group
    for (int rr = g; rr < nbin; rr += 32) {
        unsigned o0 = so0[rr], o1 = so1[rr];
        const unsigned int* p = buf + (size_t)rr * (size_t)rstride;
        for (unsigned i = o0 + l; i < o1; i += 16) {
            unsigned r = p[i];
            unsigned id = (r >> 23) & (NPB - 1);
            atomicAdd(&acc[wid][id], rec_to_val(r));
        }
    }
    __syncthreads();

    double pls = 0.0, npr = 0.0;
    for (int i = t; i < NPB; i += 512) {
        unsigned long long a = 0ull;
        #pragma unroll
        for (int w = 0; w < 8; ++w) a += acc[w][i];
        decode_accum(a, pls, npr);
    }
    for (int off = 32; off > 0; off >>= 1) {
        pls += __shfl_down(pls, off, 64);
        npr += __shfl_down(npr, off, 64);
    }
    int lane = t & 63;
    if (lane == 0) { sha[wid] = pls; shb[wid] = npr; }
    __syncthreads();
    if (t == 0) {
        double a = 0.0, c = 0.0;
        #pragma unroll
        for (int w = 0; w < 8; ++w) { a += sha[w]; c += shb[w]; }
        double* gs = (double*)hdr;
        // memory-side accumulation; consume returns so the counter atomic
        // below cannot overtake these (per-wave VMEM completes out of order)
        double r0 = atomicAdd(&gs[0], a);
        double r1 = atomicAdd(&gs[1], c);
        asm volatile("" :: "v"(r0), "v"(r1));
        __threadfence();
        unsigned long long cnt = atomicAdd(&hdr[2], 1ull);
        if (cnt == (unsigned long long)(gridDim.x - 1)) {
            // last block: totals via memory-side atomic reads
            double ta = atomicAdd(&gs[0], 0.0);
            double tb = atomicAdd(&gs[1], 0.0);
            out[0] = (float)(ta / fmax(tb, 1.0));
        }
    }
}

// ---------------- final: sum partials, divide (FALLBACK PATH ONLY) ----------
__global__ __launch_bounds__(256) void final_kernel(
    const double* __restrict__ partials,
    float* __restrict__ out,
    int nb)
{
    double pls = 0.0, npr = 0.0;
    for (int i = threadIdx.x; i < nb; i += blockDim.x) {
        pls += partials[2 * i + 0];
        npr += partials[2 * i + 1];
    }
    __shared__ double sha[4], shb[4];
    for (int off = 32; off > 0; off >>= 1) {
        pls += __shfl_down(pls, off, 64);
        npr += __shfl_down(npr, off, 64);
    }
    int lane = threadIdx.x & 63;
    int wid = threadIdx.x >> 6;
    if (lane == 0) { sha[wid] = pls; shb[wid] = npr; }
    __syncthreads();
    if (threadIdx.x == 0) {
        double a = sha[0] + sha[1] + sha[2] + sha[3];
        double b = shb[0] + shb[1] + shb[2] + shb[3];
        out[0] = (float)(a / fmax(b, 1.0));
    }
}

// ---------------- fallback path (proven): device atomics --------------------
__global__ __launch_bounds__(256) void edge_kernel_fb(
    const float2* __restrict__ pos,
    const int* __restrict__ ei,
    unsigned long long* __restrict__ acc,
    int E)
{
    int tid = blockIdx.x * blockDim.x + threadIdx.x;
    int nthreads = gridDim.x * blockDim.x;
    const int* src = ei;
    const int* dst = ei + E;
    for (int e = tid; e < E; e += nthreads) {
        int s = src[e], t = dst[e];
        float2 ps = pos[s], pt = pos[t];
        unsigned long long val = rec_to_val(make_record(pt.x - ps.x, pt.y - ps.y));
        atomicAdd(&acc[s], val);
        atomicAdd(&acc[t], val);
    }
}

__global__ __launch_bounds__(256) void node_kernel_fb(
    const unsigned long long* __restrict__ acc,
    double* __restrict__ partials,
    int N)
{
    int tid = blockIdx.x * blockDim.x + threadIdx.x;
    int nthreads = gridDim.x * blockDim.x;
    double pls = 0.0, npr = 0.0;
    for (int n = tid; n < N; n += nthreads)
        decode_accum(acc[n], pls, npr);
    __shared__ double sha[4], shb[4];
    for (int off = 32; off > 0; off >>= 1) {
        pls += __shfl_down(pls, off, 64);
        npr += __shfl_down(npr, off, 64);
    }
    int lane = threadIdx.x & 63;
    int wid = threadIdx.x >> 6;
    if (lane == 0) { sha[wid] = pls; shb[wid] = npr; }
    __syncthreads();
    if (threadIdx.x == 0) {
        partials[2 * blockIdx.x + 0] = sha[0] + sha[1] + sha[2] + sha[3];
        partials[2 * blockIdx.x + 1] = shb[0] + shb[1] + shb[2] + shb[3];
    }
}

extern "C" void kernel_launch(void* const* d_in, const int* in_sizes, int n_in,
                              void* d_out, int out_size, void* d_ws, size_t ws_size,
                              hipStream_t stream) {
    const float* pos = (const float*)d_in[0];   // (1,N,2) interleaved x,y
    const int* ei = (const int*)d_in[2];        // (2,E)
    int N = in_sizes[0] / 2;
    int E = in_sizes[2] / 2;
    float* out = (float*)d_out;

    int NB = (N + NPB - 1) >> BLOG;
    int chunk = (E + NBIN - 1) / NBIN;
    int nrec_max = 2 * chunk;
    int rstride = (nrec_max + 15) & ~15;        // 64 B-aligned regions

    // ws layout: [hdr 64B: gs0,gs1,counter,pad][buf NBIN*rstride*4][ofs ...]
    size_t off_buf = 64;
    size_t off_ofs = off_buf + (size_t)NBIN * (size_t)rstride * 4;
    size_t need = off_ofs + (size_t)NBIN * (size_t)(NB + 1) * 2;

    if (ws_size >= need && chunk <= CHMAX && NB + 1 <= 512 && nrec_max < 65536) {
        unsigned long long* hdr = (unsigned long long*)d_ws;
        unsigned int* buf = (unsigned int*)((char*)d_ws + off_buf);
        unsigned short* ofs = (unsigned short*)((char*)d_ws + off_ofs);

        bin_kernel<<<NBIN, 256, 0, stream>>>(
            (const float2*)pos, ei, E, NB, chunk, rstride, ofs, buf, hdr);
        bucket_kernel<<<NB, 512, 0, stream>>>(buf, ofs, rstride, NB, NBIN, hdr, out);
    } else {
        // fallback: device-atomic accumulation (proven path)
        unsigned long long* acc = (unsigned long long*)d_ws;
        double* partials = (double*)((char*)d_ws + (size_t)N * 8);
        hipMemsetAsync(d_ws, 0, (size_t)N * 8 + (size_t)NODE_BLOCKS * 16, stream);
        int eb = min((E + 255) / 256, 2048);
        edge_kernel_fb<<<eb, 256, 0, stream>>>((const float2*)pos, ei, acc, E);
        node_kernel_fb<<<NODE_BLOCKS, 256, 0, stream>>>(acc, partials, N);
        final_kernel<<<1, 256, 0, stream>>>(partials, out, NODE_BLOCKS);
    }
}

// Round 4
// 106.713 us; speedup vs baseline: 1.1481x; 1.1481x over previous
//
#include <hip/hip_runtime.h>
#include <math.h>

#define EPSV 1e-8f

// ---------------- math ------------------------------------------------------
// Per node n with unit incident dirs d_i = (cos phi_i, sin phi_i):
//   0.5*(S2-S4) = (u^2 - C^2 - S^2)/16,  C = sum cos(4 phi_i), S = sum sin(4 phi_i)
//   u = deg - z (z = zero-length self-edge dirs, which contribute nothing)
// Record (u32): [31] z | [30:23] local node id (8b) | [22:11] c4q | [10:0] s4q
// Accumulator (u64): {z:4 @60 | deg:8 @52 | c4sum:26 @26 | s4sum:26 @0}
//
// ROUND-1 LESSON: global atomics on gfx950 execute memory-side (past XCD L2):
//   4M u64 atomics -> ~128 MB HBM WRITE_SIZE, 181 us. Scatter-by-atomics dead.
// ROUND-2 LESSON: bucket_kernel's global READ pattern is off the critical path.
// ROUND-3 LESSON: shuffling work between bin's two passes (recbuf) REGRESSED
//   (+7 us); fused-final also reverted. bin is latency-bound at 2 waves/SIMD.
// ROUND-4 BET: bin with 512 threads (4 waves/SIMD), edges staged in LDS
//   (read once, int4), vectorized copy-out. bucket/final = round-2 proven.
static constexpr double QC = 1.0 / 1024.0;
static constexpr double QS = 1.0 / 512.0;

static constexpr int BLOG = 8;               // 256 nodes per bucket
static constexpr int NPB = 1 << BLOG;
static constexpr int NBIN = 512;             // bin blocks (each sorts its own chunk)
static constexpr int SRTN = 8192;            // LDS sort capacity (records)
static constexpr int SDMAX = 4096;           // LDS edge-stage capacity (edges)
static constexpr int NODE_BLOCKS = 256;      // fallback path

__device__ __forceinline__ unsigned int make_record(float dx, float dy) {
    float n2 = dx * dx + dy * dy;
    if (n2 > EPSV * EPSV) {
        float inv = 1.0f / n2;
        // double angle twice without sqrt: c2=cos2phi, s2=sin2phi from (dx,dy)
        float c2 = (dx * dx - dy * dy) * inv;
        float s2 = (2.0f * dx * dy) * inv;
        float c4 = c2 * c2 - s2 * s2;
        float s4 = 2.0f * c2 * s2;
        c4 = fminf(fmaxf(c4, -1.0f), 1.0f);
        s4 = fminf(fmaxf(s4, -1.0f), 1.0f);
        unsigned int c4q = (unsigned int)__float2int_rn((c4 + 1.0f) * 1024.0f);
        unsigned int s4q = (unsigned int)__float2int_rn((s4 + 1.0f) * 512.0f);
        return (c4q << 11) | s4q;
    }
    return (1u << 31) | (1024u << 11) | 512u;   // zero-length dir (self-edge)
}

__device__ __forceinline__ unsigned long long rec_to_val(unsigned int r) {
    return (((unsigned long long)(r >> 31)) << 60) | (1ull << 52)
         | (((unsigned long long)((r >> 11) & 0xFFFu)) << 26)
         | (unsigned long long)(r & 0x7FFu);
}

__device__ __forceinline__ void decode_accum(unsigned long long a, double& pls, double& npr) {
    double s4sum = (double)(a & 0x3FFFFFFull);
    double c4sum = (double)((a >> 26) & 0x3FFFFFFull);
    double deg = (double)((a >> 52) & 0xFFull);
    double z = (double)(a >> 60);
    double u = deg - z;
    double C = c4sum * QC - deg;
    double S = s4sum * QS - deg;
    pls += (u * u - C * C - S * S) * 0.0625;
    npr += 0.5 * deg * (deg - 1.0);
}

// ---------------- phase 1: per-block counting sort of records ---------------
// 512 threads (8 waves -> with 2 blocks/CU = 4 waves/SIMD, was 2).
// Pass 1: int4 vector-load edges ONCE into LDS (sdu/sdv) + histogram.
// Pass 2: s,d from LDS, gather pos, make_record, place via LDS cursors.
// LDS: srt 32K + sdu 16K + sdv 16K + hist 2K + scan 2K = 68 KB; residency is
// grid-capped at 2 blocks/CU (512 blocks / 256 CU) so this is free.
__global__ __launch_bounds__(512) void bin_kernel(
    const float2* __restrict__ pos,
    const int* __restrict__ ei,        // (2,E): src row then dst row
    int E, int NB, int chunk, int rstride,
    unsigned short* __restrict__ ofs_out,  // [NBIN][NB+1] exclusive offsets
    unsigned int* __restrict__ buf)        // [NBIN][rstride] sorted records
{
    __shared__ __align__(16) unsigned int srt[SRTN];
    __shared__ __align__(16) int sdu[SDMAX];
    __shared__ __align__(16) int sdv[SDMAX];
    __shared__ unsigned int hist[512];   // counts, then cursors
    __shared__ unsigned int scan[512];
    int blk = blockIdx.x;
    int t = threadIdx.x;
    int e0 = blk * chunk;
    int e1 = min(E, e0 + chunk);
    int cl = max(0, e1 - e0);
    const int* src = ei + e0;
    const int* dst = ei + E + e0;

    hist[t] = 0;
    __syncthreads();
    // pass 1: stage edges in LDS (vectorized when aligned) + histogram
    if (((E & 3) == 0)) {           // chunk%8==0 host-side => e0%4==0, cl%4==0
        int nq = cl >> 2;
        for (int q = t; q < nq; q += 512) {
            int4 s4 = ((const int4*)src)[q];
            int4 d4 = ((const int4*)dst)[q];
            ((int4*)sdu)[q] = s4;
            ((int4*)sdv)[q] = d4;
            atomicAdd(&hist[s4.x >> BLOG], 1u);
            atomicAdd(&hist[s4.y >> BLOG], 1u);
            atomicAdd(&hist[s4.z >> BLOG], 1u);
            atomicAdd(&hist[s4.w >> BLOG], 1u);
            atomicAdd(&hist[d4.x >> BLOG], 1u);
            atomicAdd(&hist[d4.y >> BLOG], 1u);
            atomicAdd(&hist[d4.z >> BLOG], 1u);
            atomicAdd(&hist[d4.w >> BLOG], 1u);
        }
    } else {
        for (int i = t; i < cl; i += 512) {
            int s = src[i], d = dst[i];
            sdu[i] = s; sdv[i] = d;
            atomicAdd(&hist[s >> BLOG], 1u);
            atomicAdd(&hist[d >> BLOG], 1u);
        }
    }
    __syncthreads();
    // inclusive Hillis-Steele scan over 512 slots, 1 elem/thread
    scan[t] = hist[t];
    __syncthreads();
    for (int d = 1; d < 512; d <<= 1) {
        unsigned a = scan[t] + ((t >= d) ? scan[t - d] : 0u);
        __syncthreads();
        scan[t] = a;
        __syncthreads();
    }
    // exclusive offsets; emit row; convert hist -> cursors
    unsigned ex = scan[t] - hist[t];
    size_t row = (size_t)blk * (size_t)(NB + 1);
    if (t < NB) ofs_out[row + t] = (unsigned short)ex;
    if (t == 0) ofs_out[row + NB] = (unsigned short)(2 * cl);
    __syncthreads();
    hist[t] = ex;
    __syncthreads();
    // pass 2: s,d from LDS; gather pos; compute record; place via cursors
    for (int i = t; i < cl; i += 512) {
        int s = sdu[i], d = sdv[i];
        float2 ps = pos[s], pd = pos[d];
        unsigned int rec = make_record(pd.x - ps.x, pd.y - ps.y);
        unsigned is = atomicAdd(&hist[s >> BLOG], 1u);
        srt[is] = rec | ((unsigned)(s & (NPB - 1)) << 23);
        unsigned it = atomicAdd(&hist[d >> BLOG], 1u);
        srt[it] = rec | ((unsigned)(d & (NPB - 1)) << 23);
    }
    __syncthreads();
    // coalesced copy-out of the block's private sorted region (vectorized)
    unsigned int* dstb = buf + (size_t)blk * (size_t)rstride;
    int nrec = 2 * cl;
    if ((nrec & 3) == 0) {
        int nv = nrec >> 2;
        for (int i = t; i < nv; i += 512)
            ((uint4*)dstb)[i] = ((const uint4*)srt)[i];
    } else {
        for (int i = t; i < nrec; i += 512) dstb[i] = srt[i];
    }
}

// ---------------- phase 2: per-bucket LDS reduction (round-2 proven) --------
__global__ __launch_bounds__(512) void bucket_kernel(
    const unsigned int* __restrict__ buf,
    const unsigned short* __restrict__ ofs,
    int rstride, int NB, int nbin,
    double* __restrict__ partials)     // 2 doubles per bucket
{
    __shared__ unsigned long long acc[8][NPB];   // replicated per wave (8 waves)
    __shared__ unsigned int so0[NBIN], so1[NBIN];
    __shared__ double sha[8], shb[8];
    int b = blockIdx.x;
    int t = threadIdx.x;
    int wid = t >> 6;
    for (int i = t; i < 8 * NPB; i += 512)
        ((unsigned long long*)acc)[i] = 0ull;
    // stage this bucket's run offsets (one strided burst)
    if (t < nbin) {
        size_t row = (size_t)t * (size_t)(NB + 1);
        so0[t] = ofs[row + b];
        so1[t] = ofs[row + b + 1];
    }
    __syncthreads();

    int g = t >> 4;          // group id 0..31
    int l = t & 15;          // lane within group
    for (int rr = g; rr < nbin; rr += 32) {
        unsigned o0 = so0[rr], o1 = so1[rr];
        const unsigned int* p = buf + (size_t)rr * (size_t)rstride;
        for (unsigned i = o0 + l; i < o1; i += 16) {
            unsigned r = p[i];
            unsigned id = (r >> 23) & (NPB - 1);
            atomicAdd(&acc[wid][id], rec_to_val(r));
        }
    }
    __syncthreads();

    double pls = 0.0, npr = 0.0;
    for (int i = t; i < NPB; i += 512) {
        unsigned long long a = 0ull;
        #pragma unroll
        for (int w = 0; w < 8; ++w) a += acc[w][i];
        decode_accum(a, pls, npr);
    }
    for (int off = 32; off > 0; off >>= 1) {
        pls += __shfl_down(pls, off, 64);
        npr += __shfl_down(npr, off, 64);
    }
    int lane = t & 63;
    if (lane == 0) { sha[wid] = pls; shb[wid] = npr; }
    __syncthreads();
    if (t == 0) {
        double a = 0.0, c = 0.0;
        #pragma unroll
        for (int w = 0; w < 8; ++w) { a += sha[w]; c += shb[w]; }
        partials[2 * b + 0] = a;
        partials[2 * b + 1] = c;
    }
}

// ---------------- final: sum partials, divide -------------------------------
__global__ __launch_bounds__(256) void final_kernel(
    const double* __restrict__ partials,
    float* __restrict__ out,
    int nb)
{
    double pls = 0.0, npr = 0.0;
    for (int i = threadIdx.x; i < nb; i += blockDim.x) {
        pls += partials[2 * i + 0];
        npr += partials[2 * i + 1];
    }
    __shared__ double sha[4], shb[4];
    for (int off = 32; off > 0; off >>= 1) {
        pls += __shfl_down(pls, off, 64);
        npr += __shfl_down(npr, off, 64);
    }
    int lane = threadIdx.x & 63;
    int wid = threadIdx.x >> 6;
    if (lane == 0) { sha[wid] = pls; shb[wid] = npr; }
    __syncthreads();
    if (threadIdx.x == 0) {
        double a = sha[0] + sha[1] + sha[2] + sha[3];
        double b = shb[0] + shb[1] + shb[2] + shb[3];
        out[0] = (float)(a / fmax(b, 1.0));
    }
}

// ---------------- fallback path (proven): device atomics --------------------
__global__ __launch_bounds__(256) void edge_kernel_fb(
    const float2* __restrict__ pos,
    const int* __restrict__ ei,
    unsigned long long* __restrict__ acc,
    int E)
{
    int tid = blockIdx.x * blockDim.x + threadIdx.x;
    int nthreads = gridDim.x * blockDim.x;
    const int* src = ei;
    const int* dst = ei + E;
    for (int e = tid; e < E; e += nthreads) {
        int s = src[e], t = dst[e];
        float2 ps = pos[s], pt = pos[t];
        unsigned long long val = rec_to_val(make_record(pt.x - ps.x, pt.y - ps.y));
        atomicAdd(&acc[s], val);
        atomicAdd(&acc[t], val);
    }
}

__global__ __launch_bounds__(256) void node_kernel_fb(
    const unsigned long long* __restrict__ acc,
    double* __restrict__ partials,
    int N)
{
    int tid = blockIdx.x * blockDim.x + threadIdx.x;
    int nthreads = gridDim.x * blockDim.x;
    double pls = 0.0, npr = 0.0;
    for (int n = tid; n < N; n += nthreads)
        decode_accum(acc[n], pls, npr);
    __shared__ double sha[4], shb[4];
    for (int off = 32; off > 0; off >>= 1) {
        pls += __shfl_down(pls, off, 64);
        npr += __shfl_down(npr, off, 64);
    }
    int lane = threadIdx.x & 63;
    int wid = threadIdx.x >> 6;
    if (lane == 0) { sha[wid] = pls; shb[wid] = npr; }
    __syncthreads();
    if (threadIdx.x == 0) {
        partials[2 * blockIdx.x + 0] = sha[0] + sha[1] + sha[2] + sha[3];
        partials[2 * blockIdx.x + 1] = shb[0] + shb[1] + shb[2] + shb[3];
    }
}

extern "C" void kernel_launch(void* const* d_in, const int* in_sizes, int n_in,
                              void* d_out, int out_size, void* d_ws, size_t ws_size,
                              hipStream_t stream) {
    const float* pos = (const float*)d_in[0];   // (1,N,2) interleaved x,y
    const int* ei = (const int*)d_in[2];        // (2,E)
    int N = in_sizes[0] / 2;
    int E = in_sizes[2] / 2;
    float* out = (float*)d_out;

    int NB = (N + NPB - 1) >> BLOG;
    int chunk = ((E + NBIN - 1) / NBIN + 7) & ~7;   // %8==0 -> e0%4==0, cl%4==0
    int nrec_max = 2 * chunk;
    int rstride = (nrec_max + 15) & ~15;        // 64 B-aligned regions

    // ws layout: [partials NB*16][buf NBIN*rstride*4][ofs NBIN*(NB+1)*2]
    size_t off_buf = (size_t)NB * 16;
    size_t off_ofs = off_buf + (size_t)NBIN * (size_t)rstride * 4;
    size_t need = off_ofs + (size_t)NBIN * (size_t)(NB + 1) * 2;

    if (ws_size >= need && chunk <= SDMAX && nrec_max <= SRTN
        && NB + 1 <= 512 && nrec_max < 65536) {
        double* partials = (double*)d_ws;
        unsigned int* buf = (unsigned int*)((char*)d_ws + off_buf);
        unsigned short* ofs = (unsigned short*)((char*)d_ws + off_ofs);

        bin_kernel<<<NBIN, 512, 0, stream>>>(
            (const float2*)pos, ei, E, NB, chunk, rstride, ofs, buf);
        bucket_kernel<<<NB, 512, 0, stream>>>(buf, ofs, rstride, NB, NBIN, partials);
        final_kernel<<<1, 256, 0, stream>>>(partials, out, NB);
    } else {
        // fallback: device-atomic accumulation (proven path)
        unsigned long long* acc = (unsigned long long*)d_ws;
        double* partials = (double*)((char*)d_ws + (size_t)N * 8);
        hipMemsetAsync(d_ws, 0, (size_t)N * 8 + (size_t)NODE_BLOCKS * 16, stream);
        int eb = min((E + 255) / 256, 2048);
        edge_kernel_fb<<<eb, 256, 0, stream>>>((const float2*)pos, ei, acc, E);
        node_kernel_fb<<<NODE_BLOCKS, 256, 0, stream>>>(acc, partials, N);
        final_kernel<<<1, 256, 0, stream>>>(partials, out, NODE_BLOCKS);
    }
}